// Round 3
// baseline (596.319 us; speedup 1.0000x reference)
//
#include <hip/hip_runtime.h>
#include <hip/hip_bf16.h>

// ---------------------------------------------------------------------------
// Kernel A: fused dense1+dense2.  h2 = relu(relu(x@w1+b1)@w2+b2)
// (unchanged — isolating kernel-B changes)
// ---------------------------------------------------------------------------
__launch_bounds__(256)
__global__ void fused_mlp12(const float* __restrict__ x,
                            const float* __restrict__ w1, const float* __restrict__ b1,
                            const float* __restrict__ w2, const float* __restrict__ b2,
                            float* __restrict__ h2out) {
  constexpr int BM = 64, KC = 20, BMP = 68;  // BMP*4B = 272B, 16B-aligned rows
  __shared__ float At[KC * BMP];    // 5.4 KB  staging: x^T chunk [k][r]
  __shared__ float Ws[KC * 128];    // 10.2 KB staging: weight chunk [k][c], cols padded
  __shared__ float h1T[100 * BMP];  // 27.2 KB h1 transposed [k][r]

  const int t = threadIdx.x;
  const int tx = t & 31;
  const int ty = t >> 5;
  const int rowBase = blockIdx.x * BM;

  float acc[8][4];
#pragma unroll
  for (int i = 0; i < 8; i++)
#pragma unroll
    for (int j = 0; j < 4; j++) acc[i][j] = 0.0f;

  // ---- GEMM 1: x(64x200) @ w1(200x100) ----
  for (int kc = 0; kc < 200; kc += KC) {
#pragma unroll
    for (int i = t; i < BM * KC; i += 256) {
      int r = i / KC, k = i - r * KC;
      At[k * BMP + r] = x[(rowBase + r) * 200 + kc + k];
    }
#pragma unroll
    for (int i = t; i < KC * 128; i += 256) {
      int k = i >> 7, c = i & 127;
      Ws[i] = (c < 100) ? w1[(kc + k) * 100 + c] : 0.0f;
    }
    __syncthreads();
#pragma unroll
    for (int k = 0; k < KC; k++) {
      float a[8], b[4];
      *(float4*)&a[0] = *(const float4*)&At[k * BMP + ty * 8];
      *(float4*)&a[4] = *(const float4*)&At[k * BMP + ty * 8 + 4];
      *(float4*)&b[0] = *(const float4*)&Ws[k * 128 + tx * 4];
#pragma unroll
      for (int i = 0; i < 8; i++)
#pragma unroll
        for (int j = 0; j < 4; j++) acc[i][j] += a[i] * b[j];
    }
    __syncthreads();
  }

  // h1 (bias+relu) -> LDS transposed [k][r]
  if (tx < 25) {
#pragma unroll
    for (int i = 0; i < 8; i++) {
      const int r = ty * 8 + i;
#pragma unroll
      for (int j = 0; j < 4; j++) {
        const int c = tx * 4 + j;
        h1T[c * BMP + r] = fmaxf(acc[i][j] + b1[c], 0.0f);
      }
    }
  }
  __syncthreads();

  // ---- GEMM 2: h1(64x100) @ w2(100x100) ----
#pragma unroll
  for (int i = 0; i < 8; i++)
#pragma unroll
    for (int j = 0; j < 4; j++) acc[i][j] = 0.0f;

  for (int kc = 0; kc < 100; kc += KC) {
#pragma unroll
    for (int i = t; i < KC * 128; i += 256) {
      int k = i >> 7, c = i & 127;
      Ws[i] = (c < 100) ? w2[(kc + k) * 100 + c] : 0.0f;
    }
    __syncthreads();
#pragma unroll
    for (int k = 0; k < KC; k++) {
      float a[8], b[4];
      *(float4*)&a[0] = *(const float4*)&h1T[(kc + k) * BMP + ty * 8];
      *(float4*)&a[4] = *(const float4*)&h1T[(kc + k) * BMP + ty * 8 + 4];
      *(float4*)&b[0] = *(const float4*)&Ws[k * 128 + tx * 4];
#pragma unroll
      for (int i = 0; i < 8; i++)
#pragma unroll
        for (int j = 0; j < 4; j++) acc[i][j] += a[i] * b[j];
    }
    __syncthreads();
  }

  if (tx < 25) {
#pragma unroll
    for (int i = 0; i < 8; i++) {
      const int r = rowBase + ty * 8 + i;
      float4 v;
      v.x = fmaxf(acc[i][0] + b2[tx * 4 + 0], 0.0f);
      v.y = fmaxf(acc[i][1] + b2[tx * 4 + 1], 0.0f);
      v.z = fmaxf(acc[i][2] + b2[tx * 4 + 2], 0.0f);
      v.w = fmaxf(acc[i][3] + b2[tx * 4 + 3], 0.0f);
      *(float4*)&h2out[r * 100 + tx * 4] = v;
    }
  }
}

// ---------------------------------------------------------------------------
// Kernel B: fused logits-GEMM + SampleConcrete + head.
// Round-3 change (post-mortem R2: VALU 30% / HBM 14% both idle, occupancy
// GRID-capped at 2 blocks/CU; latency model 4 waves/SIMD x 500cy compute /
// 1400cy row-cycle ~= 30% VALU — matched measurement):
//   BM 64 -> 32: grid 512 -> 1024 blocks = 4 blocks/CU = 8 waves/SIMD
//   (100% occupancy cap). LDS 51.2 -> 25.6 KB (staging 23.4 KB still
//   aliases under lg). Phase-1 micro-tile 4x8 -> 2x8; phase-2 waves own
//   4 rows instead of 8. __launch_bounds__(512,8) caps VGPR at 64
//   (compiler's natural allocation was 48 — no spill expected).
// Everything else identical to R2 (40-deep uniform batch, factorized
// gumbel-softmax, interleaved butterflies, nontemporal samples store).
// ---------------------------------------------------------------------------
__launch_bounds__(512, 8)
__global__ void fused_logits_concrete(const float* __restrict__ x,
                                      const float* __restrict__ uniform,
                                      const float* __restrict__ h2,
                                      const float* __restrict__ wl, const float* __restrict__ bl,
                                      const float* __restrict__ wo, const float* __restrict__ bo,
                                      float* __restrict__ out, int B) {
  constexpr int BM = 32, KC = 20, BMP = 36;  // BMP*4B = 144B, 16B-aligned rows
  constexpr float EPS = 1.1920929e-07f;
  // 25.6 KB total: staging (At 720 + Ws 5120 floats = 5840) aliases lg[6400].
  __shared__ float smem[BM * 200];
  float* const At = smem;             // [KC][BMP]   (phase 1 only)
  float* const Ws = smem + KC * BMP;  // [KC][256]   (phase 1 only)
  float* const lg = smem;             // [BM][200]   (written after last GEMM sync)

  const int t = threadIdx.x;
  const int rowBase = blockIdx.x * BM;

  // ---- Phase 1: logits = h2(32x100) @ wl(100x200) + bl ----
  {
    const int tx = t & 31;
    const int ty = t >> 5;  // 0..15, rows ty*2..+1
    float acc[2][8];
#pragma unroll
    for (int i = 0; i < 2; i++)
#pragma unroll
      for (int j = 0; j < 8; j++) acc[i][j] = 0.0f;

    for (int kc = 0; kc < 100; kc += KC) {
      for (int i = t; i < BM * KC; i += 512) {
        int r = i / KC, k = i - r * KC;
        At[k * BMP + r] = h2[(rowBase + r) * 100 + kc + k];
      }
#pragma unroll
      for (int i = t; i < KC * 256; i += 512) {
        int k = i >> 8, c = i & 255;
        Ws[i] = (c < 200) ? wl[(kc + k) * 200 + c] : 0.0f;
      }
      __syncthreads();
#pragma unroll
      for (int k = 0; k < KC; k++) {
        float a[2], b[8];
        *(float2*)&a[0] = *(const float2*)&At[k * BMP + ty * 2];  // half-wave broadcast
        *(float4*)&b[0] = *(const float4*)&Ws[k * 256 + tx * 8];
        *(float4*)&b[4] = *(const float4*)&Ws[k * 256 + tx * 8 + 4];
#pragma unroll
        for (int i = 0; i < 2; i++)
#pragma unroll
          for (int j = 0; j < 8; j++) acc[i][j] += a[i] * b[j];
      }
      __syncthreads();  // all reads of At/Ws done -> safe to overwrite with lg
    }

    if (tx < 25) {
#pragma unroll
      for (int i = 0; i < 2; i++) {
        const int r = ty * 2 + i;
        float4 v0, v1;
        v0.x = acc[i][0] + bl[tx * 8 + 0];
        v0.y = acc[i][1] + bl[tx * 8 + 1];
        v0.z = acc[i][2] + bl[tx * 8 + 2];
        v0.w = acc[i][3] + bl[tx * 8 + 3];
        v1.x = acc[i][4] + bl[tx * 8 + 4];
        v1.y = acc[i][5] + bl[tx * 8 + 5];
        v1.z = acc[i][6] + bl[tx * 8 + 6];
        v1.w = acc[i][7] + bl[tx * 8 + 7];
        *(float4*)&lg[r * 200 + tx * 8] = v0;
        *(float4*)&lg[r * 200 + tx * 8 + 4] = v1;
      }
    }
    __syncthreads();
  }

  // ---- Phase 2: SampleConcrete + head; one wave per row, 4 rows/wave ----
  const int lane = t & 63;
  const int wave = t >> 6;  // 0..7
  const size_t samplesBase = (size_t)B * 2;

#pragma unroll 1
  for (int rr = 0; rr < 4; rr++) {
    const int r = wave * 4 + rr;
    const int b = rowBase + r;
    const float* __restrict__ u = uniform + (size_t)b * 2000;

    float lgv[4], xv[4];
    bool vld[4];
#pragma unroll
    for (int i = 0; i < 4; i++) {
      const int d = lane + 64 * i;
      vld[i] = (d < 200);
      lgv[i] = vld[i] ? lg[r * 200 + d] : -1e30f;
      xv[i]  = vld[i] ? x[(size_t)b * 200 + d] : 0.0f;
    }

    // Batch ALL 10 samples' uniforms first: 40 loads in flight per lane.
    float s[10][4];
#pragma unroll
    for (int k = 0; k < 10; k++)
#pragma unroll
      for (int i = 0; i < 4; i++)
        s[k][i] = vld[i] ? u[k * 200 + lane + 64 * i] : 0.5f;

    // Row max of logits (once per row)
    float m = fmaxf(fmaxf(lgv[0], lgv[1]), fmaxf(lgv[2], lgv[3]));
#pragma unroll
    for (int off = 32; off > 0; off >>= 1) m = fmaxf(m, __shfl_xor(m, off, 64));

    // el_d = exp(2*(lg_d - lgmax)); invalid lanes -> 0 (never pollute sums)
    float el[4];
#pragma unroll
    for (int i = 0; i < 4; i++) el[i] = vld[i] ? __expf(2.0f * (lgv[i] - m)) : 0.0f;

    // In-place transform: s = el / log2(u)^2  (ln^2(2) cancels in softmax;
    // invalid lanes: u=0.5 -> q=-1 -> rcp(1)=1, times el=0 -> 0).
#pragma unroll
    for (int k = 0; k < 10; k++)
#pragma unroll
      for (int i = 0; i < 4; i++) {
        const float q = __log2f(fmaxf(s[k][i], EPS));
        s[k][i] = el[i] * __builtin_amdgcn_rcpf(q * q);
      }

    // 10 independent butterfly reductions, interleaved (pipelined shuffles)
    float ps[10];
#pragma unroll
    for (int k = 0; k < 10; k++) ps[k] = (s[k][0] + s[k][1]) + (s[k][2] + s[k][3]);
#pragma unroll
    for (int off = 32; off > 0; off >>= 1)
#pragma unroll
      for (int k = 0; k < 10; k++) ps[k] += __shfl_xor(ps[k], off, 64);
#pragma unroll
    for (int k = 0; k < 10; k++) ps[k] = __builtin_amdgcn_rcpf(ps[k]);

    float smax[4] = {0.0f, 0.0f, 0.0f, 0.0f};
#pragma unroll
    for (int k = 0; k < 10; k++)
#pragma unroll
      for (int i = 0; i < 4; i++) smax[i] = fmaxf(smax[i], s[k][i] * ps[k]);

    float p0 = 0.0f, p1 = 0.0f;
#pragma unroll
    for (int i = 0; i < 4; i++) {
      const int d = lane + 64 * i;
      if (d < 200) {
        const float sv = smax[i];
        __builtin_nontemporal_store(sv, &out[samplesBase + (size_t)b * 200 + d]);
        const float xs = xv[i] * sv;
        p0 += xs * wo[d * 2 + 0];
        p1 += xs * wo[d * 2 + 1];
      }
    }
#pragma unroll
    for (int off = 32; off > 0; off >>= 1) {
      p0 += __shfl_xor(p0, off, 64);
      p1 += __shfl_xor(p1, off, 64);
    }
    if (lane == 0) {
      const float z0 = p0 + bo[0];
      const float z1 = p1 + bo[1];
      const float mh = fmaxf(z0, z1);
      const float e0 = __expf(z0 - mh);
      const float e1 = __expf(z1 - mh);
      out[b * 2 + 0] = e0 / (e0 + e1);
      out[b * 2 + 1] = e1 / (e0 + e1);
    }
  }
}

extern "C" void kernel_launch(void* const* d_in, const int* in_sizes, int n_in,
                              void* d_out, int out_size, void* d_ws, size_t ws_size,
                              hipStream_t stream) {
  const float* x  = (const float*)d_in[0];
  const float* un = (const float*)d_in[1];
  const float* w1 = (const float*)d_in[2];
  const float* b1 = (const float*)d_in[3];
  const float* w2 = (const float*)d_in[4];
  const float* b2 = (const float*)d_in[5];
  const float* wl = (const float*)d_in[6];
  const float* bl = (const float*)d_in[7];
  const float* wo = (const float*)d_in[8];
  const float* bo = (const float*)d_in[9];
  float* out = (float*)d_out;

  const int B = in_sizes[0] / 200;  // 32768
  float* h2 = (float*)d_ws;         // B*100 fp32 = 13.1 MB

  fused_mlp12<<<B / 64, 256, 0, stream>>>(x, w1, b1, w2, b2, h2);
  fused_logits_concrete<<<B / 32, 512, 0, stream>>>(x, un, h2, wl, bl, wo, bo, out, B);
}

// Round 4
// 585.471 us; speedup vs baseline: 1.0185x; 1.0185x over previous
//
#include <hip/hip_runtime.h>
#include <hip/hip_bf16.h>

// ---------------------------------------------------------------------------
// Kernel A: fused dense1+dense2.  h2 = relu(relu(x@w1+b1)@w2+b2)
// (unchanged — isolating kernel-B changes)
// ---------------------------------------------------------------------------
__launch_bounds__(256)
__global__ void fused_mlp12(const float* __restrict__ x,
                            const float* __restrict__ w1, const float* __restrict__ b1,
                            const float* __restrict__ w2, const float* __restrict__ b2,
                            float* __restrict__ h2out) {
  constexpr int BM = 64, KC = 20, BMP = 68;  // BMP*4B = 272B, 16B-aligned rows
  __shared__ float At[KC * BMP];    // 5.4 KB  staging: x^T chunk [k][r]
  __shared__ float Ws[KC * 128];    // 10.2 KB staging: weight chunk [k][c], cols padded
  __shared__ float h1T[100 * BMP];  // 27.2 KB h1 transposed [k][r]

  const int t = threadIdx.x;
  const int tx = t & 31;
  const int ty = t >> 5;
  const int rowBase = blockIdx.x * BM;

  float acc[8][4];
#pragma unroll
  for (int i = 0; i < 8; i++)
#pragma unroll
    for (int j = 0; j < 4; j++) acc[i][j] = 0.0f;

  // ---- GEMM 1: x(64x200) @ w1(200x100) ----
  for (int kc = 0; kc < 200; kc += KC) {
#pragma unroll
    for (int i = t; i < BM * KC; i += 256) {
      int r = i / KC, k = i - r * KC;
      At[k * BMP + r] = x[(rowBase + r) * 200 + kc + k];
    }
#pragma unroll
    for (int i = t; i < KC * 128; i += 256) {
      int k = i >> 7, c = i & 127;
      Ws[i] = (c < 100) ? w1[(kc + k) * 100 + c] : 0.0f;
    }
    __syncthreads();
#pragma unroll
    for (int k = 0; k < KC; k++) {
      float a[8], b[4];
      *(float4*)&a[0] = *(const float4*)&At[k * BMP + ty * 8];
      *(float4*)&a[4] = *(const float4*)&At[k * BMP + ty * 8 + 4];
      *(float4*)&b[0] = *(const float4*)&Ws[k * 128 + tx * 4];
#pragma unroll
      for (int i = 0; i < 8; i++)
#pragma unroll
        for (int j = 0; j < 4; j++) acc[i][j] += a[i] * b[j];
    }
    __syncthreads();
  }

  // h1 (bias+relu) -> LDS transposed [k][r]
  if (tx < 25) {
#pragma unroll
    for (int i = 0; i < 8; i++) {
      const int r = ty * 8 + i;
#pragma unroll
      for (int j = 0; j < 4; j++) {
        const int c = tx * 4 + j;
        h1T[c * BMP + r] = fmaxf(acc[i][j] + b1[c], 0.0f);
      }
    }
  }
  __syncthreads();

  // ---- GEMM 2: h1(64x100) @ w2(100x100) ----
#pragma unroll
  for (int i = 0; i < 8; i++)
#pragma unroll
    for (int j = 0; j < 4; j++) acc[i][j] = 0.0f;

  for (int kc = 0; kc < 100; kc += KC) {
#pragma unroll
    for (int i = t; i < KC * 128; i += 256) {
      int k = i >> 7, c = i & 127;
      Ws[i] = (c < 100) ? w2[(kc + k) * 100 + c] : 0.0f;
    }
    __syncthreads();
#pragma unroll
    for (int k = 0; k < KC; k++) {
      float a[8], b[4];
      *(float4*)&a[0] = *(const float4*)&h1T[(kc + k) * BMP + ty * 8];
      *(float4*)&a[4] = *(const float4*)&h1T[(kc + k) * BMP + ty * 8 + 4];
      *(float4*)&b[0] = *(const float4*)&Ws[k * 128 + tx * 4];
#pragma unroll
      for (int i = 0; i < 8; i++)
#pragma unroll
        for (int j = 0; j < 4; j++) acc[i][j] += a[i] * b[j];
    }
    __syncthreads();
  }

  if (tx < 25) {
#pragma unroll
    for (int i = 0; i < 8; i++) {
      const int r = rowBase + ty * 8 + i;
      float4 v;
      v.x = fmaxf(acc[i][0] + b2[tx * 4 + 0], 0.0f);
      v.y = fmaxf(acc[i][1] + b2[tx * 4 + 1], 0.0f);
      v.z = fmaxf(acc[i][2] + b2[tx * 4 + 2], 0.0f);
      v.w = fmaxf(acc[i][3] + b2[tx * 4 + 3], 0.0f);
      *(float4*)&h2out[r * 100 + tx * 4] = v;
    }
  }
}

// ---------------------------------------------------------------------------
// Kernel B: fused logits-GEMM + SampleConcrete + head.
// Round-4 change (post-mortem R3: __launch_bounds__(512,8) => 64-VGPR budget
// => compiler allocated 32 and SPILLED the s[10][4] batch: VGPR 48->32,
// FETCH +143MB, WRITE +215MB of scratch traffic, VALUBusy 30->23% despite
// occupancy 44->86%. Occupancy bought by spilling is negative.):
//   __launch_bounds__(512,6): VGPR budget ~84 >> 48 natural usage -> no
//   spill; 3 blocks/CU (24 waves/CU, 75% cap). LDS 3x25.6=76.8KB fits.
// Everything else identical to R3 (BM=32 grid 1024, 40-deep uniform batch,
// factorized gumbel-softmax, interleaved butterflies, nontemporal stores).
// ---------------------------------------------------------------------------
__launch_bounds__(512, 6)
__global__ void fused_logits_concrete(const float* __restrict__ x,
                                      const float* __restrict__ uniform,
                                      const float* __restrict__ h2,
                                      const float* __restrict__ wl, const float* __restrict__ bl,
                                      const float* __restrict__ wo, const float* __restrict__ bo,
                                      float* __restrict__ out, int B) {
  constexpr int BM = 32, KC = 20, BMP = 36;  // BMP*4B = 144B, 16B-aligned rows
  constexpr float EPS = 1.1920929e-07f;
  // 25.6 KB total: staging (At 720 + Ws 5120 floats = 5840) aliases lg[6400].
  __shared__ float smem[BM * 200];
  float* const At = smem;             // [KC][BMP]   (phase 1 only)
  float* const Ws = smem + KC * BMP;  // [KC][256]   (phase 1 only)
  float* const lg = smem;             // [BM][200]   (written after last GEMM sync)

  const int t = threadIdx.x;
  const int rowBase = blockIdx.x * BM;

  // ---- Phase 1: logits = h2(32x100) @ wl(100x200) + bl ----
  {
    const int tx = t & 31;
    const int ty = t >> 5;  // 0..15, rows ty*2..+1
    float acc[2][8];
#pragma unroll
    for (int i = 0; i < 2; i++)
#pragma unroll
      for (int j = 0; j < 8; j++) acc[i][j] = 0.0f;

    for (int kc = 0; kc < 100; kc += KC) {
      for (int i = t; i < BM * KC; i += 512) {
        int r = i / KC, k = i - r * KC;
        At[k * BMP + r] = h2[(rowBase + r) * 100 + kc + k];
      }
#pragma unroll
      for (int i = t; i < KC * 256; i += 512) {
        int k = i >> 8, c = i & 255;
        Ws[i] = (c < 200) ? wl[(kc + k) * 200 + c] : 0.0f;
      }
      __syncthreads();
#pragma unroll
      for (int k = 0; k < KC; k++) {
        float a[2], b[8];
        *(float2*)&a[0] = *(const float2*)&At[k * BMP + ty * 2];
        *(float4*)&b[0] = *(const float4*)&Ws[k * 256 + tx * 8];
        *(float4*)&b[4] = *(const float4*)&Ws[k * 256 + tx * 8 + 4];
#pragma unroll
        for (int i = 0; i < 2; i++)
#pragma unroll
          for (int j = 0; j < 8; j++) acc[i][j] += a[i] * b[j];
      }
      __syncthreads();  // all reads of At/Ws done -> safe to overwrite with lg
    }

    if (tx < 25) {
#pragma unroll
      for (int i = 0; i < 2; i++) {
        const int r = ty * 2 + i;
        float4 v0, v1;
        v0.x = acc[i][0] + bl[tx * 8 + 0];
        v0.y = acc[i][1] + bl[tx * 8 + 1];
        v0.z = acc[i][2] + bl[tx * 8 + 2];
        v0.w = acc[i][3] + bl[tx * 8 + 3];
        v1.x = acc[i][4] + bl[tx * 8 + 4];
        v1.y = acc[i][5] + bl[tx * 8 + 5];
        v1.z = acc[i][6] + bl[tx * 8 + 6];
        v1.w = acc[i][7] + bl[tx * 8 + 7];
        *(float4*)&lg[r * 200 + tx * 8] = v0;
        *(float4*)&lg[r * 200 + tx * 8 + 4] = v1;
      }
    }
    __syncthreads();
  }

  // ---- Phase 2: SampleConcrete + head; one wave per row, 4 rows/wave ----
  const int lane = t & 63;
  const int wave = t >> 6;  // 0..7
  const size_t samplesBase = (size_t)B * 2;

#pragma unroll 1
  for (int rr = 0; rr < 4; rr++) {
    const int r = wave * 4 + rr;
    const int b = rowBase + r;
    const float* __restrict__ u = uniform + (size_t)b * 2000;

    float lgv[4], xv[4];
    bool vld[4];
#pragma unroll
    for (int i = 0; i < 4; i++) {
      const int d = lane + 64 * i;
      vld[i] = (d < 200);
      lgv[i] = vld[i] ? lg[r * 200 + d] : -1e30f;
      xv[i]  = vld[i] ? x[(size_t)b * 200 + d] : 0.0f;
    }

    // Batch ALL 10 samples' uniforms first: 40 loads in flight per lane.
    float s[10][4];
#pragma unroll
    for (int k = 0; k < 10; k++)
#pragma unroll
      for (int i = 0; i < 4; i++)
        s[k][i] = vld[i] ? u[k * 200 + lane + 64 * i] : 0.5f;

    // Row max of logits (once per row)
    float m = fmaxf(fmaxf(lgv[0], lgv[1]), fmaxf(lgv[2], lgv[3]));
#pragma unroll
    for (int off = 32; off > 0; off >>= 1) m = fmaxf(m, __shfl_xor(m, off, 64));

    // el_d = exp(2*(lg_d - lgmax)); invalid lanes -> 0 (never pollute sums)
    float el[4];
#pragma unroll
    for (int i = 0; i < 4; i++) el[i] = vld[i] ? __expf(2.0f * (lgv[i] - m)) : 0.0f;

    // In-place transform: s = el / log2(u)^2  (ln^2(2) cancels in softmax;
    // invalid lanes: u=0.5 -> q=-1 -> rcp(1)=1, times el=0 -> 0).
#pragma unroll
    for (int k = 0; k < 10; k++)
#pragma unroll
      for (int i = 0; i < 4; i++) {
        const float q = __log2f(fmaxf(s[k][i], EPS));
        s[k][i] = el[i] * __builtin_amdgcn_rcpf(q * q);
      }

    // 10 independent butterfly reductions, interleaved (pipelined shuffles)
    float ps[10];
#pragma unroll
    for (int k = 0; k < 10; k++) ps[k] = (s[k][0] + s[k][1]) + (s[k][2] + s[k][3]);
#pragma unroll
    for (int off = 32; off > 0; off >>= 1)
#pragma unroll
      for (int k = 0; k < 10; k++) ps[k] += __shfl_xor(ps[k], off, 64);
#pragma unroll
    for (int k = 0; k < 10; k++) ps[k] = __builtin_amdgcn_rcpf(ps[k]);

    float smax[4] = {0.0f, 0.0f, 0.0f, 0.0f};
#pragma unroll
    for (int k = 0; k < 10; k++)
#pragma unroll
      for (int i = 0; i < 4; i++) smax[i] = fmaxf(smax[i], s[k][i] * ps[k]);

    float p0 = 0.0f, p1 = 0.0f;
#pragma unroll
    for (int i = 0; i < 4; i++) {
      const int d = lane + 64 * i;
      if (d < 200) {
        const float sv = smax[i];
        __builtin_nontemporal_store(sv, &out[samplesBase + (size_t)b * 200 + d]);
        const float xs = xv[i] * sv;
        p0 += xs * wo[d * 2 + 0];
        p1 += xs * wo[d * 2 + 1];
      }
    }
#pragma unroll
    for (int off = 32; off > 0; off >>= 1) {
      p0 += __shfl_xor(p0, off, 64);
      p1 += __shfl_xor(p1, off, 64);
    }
    if (lane == 0) {
      const float z0 = p0 + bo[0];
      const float z1 = p1 + bo[1];
      const float mh = fmaxf(z0, z1);
      const float e0 = __expf(z0 - mh);
      const float e1 = __expf(z1 - mh);
      out[b * 2 + 0] = e0 / (e0 + e1);
      out[b * 2 + 1] = e1 / (e0 + e1);
    }
  }
}

extern "C" void kernel_launch(void* const* d_in, const int* in_sizes, int n_in,
                              void* d_out, int out_size, void* d_ws, size_t ws_size,
                              hipStream_t stream) {
  const float* x  = (const float*)d_in[0];
  const float* un = (const float*)d_in[1];
  const float* w1 = (const float*)d_in[2];
  const float* b1 = (const float*)d_in[3];
  const float* w2 = (const float*)d_in[4];
  const float* b2 = (const float*)d_in[5];
  const float* wl = (const float*)d_in[6];
  const float* bl = (const float*)d_in[7];
  const float* wo = (const float*)d_in[8];
  const float* bo = (const float*)d_in[9];
  float* out = (float*)d_out;

  const int B = in_sizes[0] / 200;  // 32768
  float* h2 = (float*)d_ws;         // B*100 fp32 = 13.1 MB

  fused_mlp12<<<B / 64, 256, 0, stream>>>(x, w1, b1, w2, b2, h2);
  fused_logits_concrete<<<B / 32, 512, 0, stream>>>(x, un, h2, wl, bl, wo, bo, out, B);
}

// Round 5
// 529.252 us; speedup vs baseline: 1.1267x; 1.1062x over previous
//
#include <hip/hip_runtime.h>
#include <hip/hip_bf16.h>

// ---------------------------------------------------------------------------
// Kernel A: fused dense1+dense2.  h2 = relu(relu(x@w1+b1)@w2+b2)
// (unchanged — isolating kernel-B changes)
// ---------------------------------------------------------------------------
__launch_bounds__(256)
__global__ void fused_mlp12(const float* __restrict__ x,
                            const float* __restrict__ w1, const float* __restrict__ b1,
                            const float* __restrict__ w2, const float* __restrict__ b2,
                            float* __restrict__ h2out) {
  constexpr int BM = 64, KC = 20, BMP = 68;  // BMP*4B = 272B, 16B-aligned rows
  __shared__ float At[KC * BMP];    // 5.4 KB  staging: x^T chunk [k][r]
  __shared__ float Ws[KC * 128];    // 10.2 KB staging: weight chunk [k][c], cols padded
  __shared__ float h1T[100 * BMP];  // 27.2 KB h1 transposed [k][r]

  const int t = threadIdx.x;
  const int tx = t & 31;
  const int ty = t >> 5;
  const int rowBase = blockIdx.x * BM;

  float acc[8][4];
#pragma unroll
  for (int i = 0; i < 8; i++)
#pragma unroll
    for (int j = 0; j < 4; j++) acc[i][j] = 0.0f;

  // ---- GEMM 1: x(64x200) @ w1(200x100) ----
  for (int kc = 0; kc < 200; kc += KC) {
#pragma unroll
    for (int i = t; i < BM * KC; i += 256) {
      int r = i / KC, k = i - r * KC;
      At[k * BMP + r] = x[(rowBase + r) * 200 + kc + k];
    }
#pragma unroll
    for (int i = t; i < KC * 128; i += 256) {
      int k = i >> 7, c = i & 127;
      Ws[i] = (c < 100) ? w1[(kc + k) * 100 + c] : 0.0f;
    }
    __syncthreads();
#pragma unroll
    for (int k = 0; k < KC; k++) {
      float a[8], b[4];
      *(float4*)&a[0] = *(const float4*)&At[k * BMP + ty * 8];
      *(float4*)&a[4] = *(const float4*)&At[k * BMP + ty * 8 + 4];
      *(float4*)&b[0] = *(const float4*)&Ws[k * 128 + tx * 4];
#pragma unroll
      for (int i = 0; i < 8; i++)
#pragma unroll
        for (int j = 0; j < 4; j++) acc[i][j] += a[i] * b[j];
    }
    __syncthreads();
  }

  // h1 (bias+relu) -> LDS transposed [k][r]
  if (tx < 25) {
#pragma unroll
    for (int i = 0; i < 8; i++) {
      const int r = ty * 8 + i;
#pragma unroll
      for (int j = 0; j < 4; j++) {
        const int c = tx * 4 + j;
        h1T[c * BMP + r] = fmaxf(acc[i][j] + b1[c], 0.0f);
      }
    }
  }
  __syncthreads();

  // ---- GEMM 2: h1(64x100) @ w2(100x100) ----
#pragma unroll
  for (int i = 0; i < 8; i++)
#pragma unroll
    for (int j = 0; j < 4; j++) acc[i][j] = 0.0f;

  for (int kc = 0; kc < 100; kc += KC) {
#pragma unroll
    for (int i = t; i < KC * 128; i += 256) {
      int k = i >> 7, c = i & 127;
      Ws[i] = (c < 100) ? w2[(kc + k) * 100 + c] : 0.0f;
    }
    __syncthreads();
#pragma unroll
    for (int k = 0; k < KC; k++) {
      float a[8], b[4];
      *(float4*)&a[0] = *(const float4*)&h1T[(kc + k) * BMP + ty * 8];
      *(float4*)&a[4] = *(const float4*)&h1T[(kc + k) * BMP + ty * 8 + 4];
      *(float4*)&b[0] = *(const float4*)&Ws[k * 128 + tx * 4];
#pragma unroll
      for (int i = 0; i < 8; i++)
#pragma unroll
        for (int j = 0; j < 4; j++) acc[i][j] += a[i] * b[j];
    }
    __syncthreads();
  }

  if (tx < 25) {
#pragma unroll
    for (int i = 0; i < 8; i++) {
      const int r = rowBase + ty * 8 + i;
      float4 v;
      v.x = fmaxf(acc[i][0] + b2[tx * 4 + 0], 0.0f);
      v.y = fmaxf(acc[i][1] + b2[tx * 4 + 1], 0.0f);
      v.z = fmaxf(acc[i][2] + b2[tx * 4 + 2], 0.0f);
      v.w = fmaxf(acc[i][3] + b2[tx * 4 + 3], 0.0f);
      *(float4*)&h2out[r * 100 + tx * 4] = v;
    }
  }
}

// ---------------------------------------------------------------------------
// Kernel B: fused logits-GEMM + SampleConcrete + head.
// Round-5 change (post-mortem R3/R4: gfx950 VGPR allocation classes are
// {<=64 -> 8 waves/SIMD, <=128 -> 4, <=256 -> 2} (m69). launch_bounds(512,6)
// and (512,8) both force the 64-class; natural demand ~52 (s[10][4]=40 live)
// doesn't fit -> compiler spilled ~12 dwords/thread (FETCH/WRITE +26MB each),
// occupancy gain nullified. The binding constraint is the 40-reg batch.):
//   Split the 10-sample batch into TWO 5-sample passes: s[5][4]=20 regs.
//   #pragma unroll 1 on the half-loop prevents re-fusion (all s/ps indices
//   remain compile-time static — no scratch per rule #20). x reload moved
//   after the sampling loop so xv isn't live across it. Worst-case live
//   ~47 regs -> fits the 64-class -> 8 waves/SIMD, 4 blocks/CU, no spill.
//   ILP per pass halves (20 loads in flight); 2x TLP is the bet.
// Everything else identical (BM=32 grid 1024, factorized gumbel-softmax,
// interleaved butterflies, nontemporal stores, LDS union 25.6KB).
// ---------------------------------------------------------------------------
__launch_bounds__(512, 8)
__global__ void fused_logits_concrete(const float* __restrict__ x,
                                      const float* __restrict__ uniform,
                                      const float* __restrict__ h2,
                                      const float* __restrict__ wl, const float* __restrict__ bl,
                                      const float* __restrict__ wo, const float* __restrict__ bo,
                                      float* __restrict__ out, int B) {
  constexpr int BM = 32, KC = 20, BMP = 36;  // BMP*4B = 144B, 16B-aligned rows
  constexpr float EPS = 1.1920929e-07f;
  // 25.6 KB total: staging (At 720 + Ws 5120 floats = 5840) aliases lg[6400].
  __shared__ float smem[BM * 200];
  float* const At = smem;             // [KC][BMP]   (phase 1 only)
  float* const Ws = smem + KC * BMP;  // [KC][256]   (phase 1 only)
  float* const lg = smem;             // [BM][200]   (written after last GEMM sync)

  const int t = threadIdx.x;
  const int rowBase = blockIdx.x * BM;

  // ---- Phase 1: logits = h2(32x100) @ wl(100x200) + bl ----
  {
    const int tx = t & 31;
    const int ty = t >> 5;  // 0..15, rows ty*2..+1
    float acc[2][8];
#pragma unroll
    for (int i = 0; i < 2; i++)
#pragma unroll
      for (int j = 0; j < 8; j++) acc[i][j] = 0.0f;

    for (int kc = 0; kc < 100; kc += KC) {
      for (int i = t; i < BM * KC; i += 512) {
        int r = i / KC, k = i - r * KC;
        At[k * BMP + r] = h2[(rowBase + r) * 100 + kc + k];
      }
#pragma unroll
      for (int i = t; i < KC * 256; i += 512) {
        int k = i >> 8, c = i & 255;
        Ws[i] = (c < 200) ? wl[(kc + k) * 200 + c] : 0.0f;
      }
      __syncthreads();
#pragma unroll
      for (int k = 0; k < KC; k++) {
        float a[2], b[8];
        *(float2*)&a[0] = *(const float2*)&At[k * BMP + ty * 2];
        *(float4*)&b[0] = *(const float4*)&Ws[k * 256 + tx * 8];
        *(float4*)&b[4] = *(const float4*)&Ws[k * 256 + tx * 8 + 4];
#pragma unroll
        for (int i = 0; i < 2; i++)
#pragma unroll
          for (int j = 0; j < 8; j++) acc[i][j] += a[i] * b[j];
      }
      __syncthreads();  // all reads of At/Ws done -> safe to overwrite with lg
    }

    if (tx < 25) {
#pragma unroll
      for (int i = 0; i < 2; i++) {
        const int r = ty * 2 + i;
        float4 v0, v1;
        v0.x = acc[i][0] + bl[tx * 8 + 0];
        v0.y = acc[i][1] + bl[tx * 8 + 1];
        v0.z = acc[i][2] + bl[tx * 8 + 2];
        v0.w = acc[i][3] + bl[tx * 8 + 3];
        v1.x = acc[i][4] + bl[tx * 8 + 4];
        v1.y = acc[i][5] + bl[tx * 8 + 5];
        v1.z = acc[i][6] + bl[tx * 8 + 6];
        v1.w = acc[i][7] + bl[tx * 8 + 7];
        *(float4*)&lg[r * 200 + tx * 8] = v0;
        *(float4*)&lg[r * 200 + tx * 8 + 4] = v1;
      }
    }
    __syncthreads();
  }

  // ---- Phase 2: SampleConcrete + head; one wave per row, 4 rows/wave ----
  const int lane = t & 63;
  const int wave = t >> 6;  // 0..7
  const size_t samplesBase = (size_t)B * 2;

#pragma unroll 1
  for (int rr = 0; rr < 4; rr++) {
    const int r = wave * 4 + rr;
    const int b = rowBase + r;
    const float* __restrict__ u = uniform + (size_t)b * 2000;

    bool vld[4];
    float el[4];
    {
      float lgv[4];
#pragma unroll
      for (int i = 0; i < 4; i++) {
        const int d = lane + 64 * i;
        vld[i] = (d < 200);
        lgv[i] = vld[i] ? lg[r * 200 + d] : -1e30f;
      }
      // Row max of logits (once per row)
      float m = fmaxf(fmaxf(lgv[0], lgv[1]), fmaxf(lgv[2], lgv[3]));
#pragma unroll
      for (int off = 32; off > 0; off >>= 1) m = fmaxf(m, __shfl_xor(m, off, 64));
      // el_d = exp(2*(lg_d - lgmax)); invalid lanes -> 0
#pragma unroll
      for (int i = 0; i < 4; i++) el[i] = vld[i] ? __expf(2.0f * (lgv[i] - m)) : 0.0f;
    }

    float smax[4] = {0.0f, 0.0f, 0.0f, 0.0f};

    // Two passes of 5 samples each: s[5][4]=20 regs live (fits the 64-VGPR
    // allocation class at 8 waves/SIMD). unroll 1 => compiler cannot fuse
    // the halves back into a 40-reg batch; all s/ps indices remain static.
#pragma unroll 1
    for (int half = 0; half < 2; half++) {
      const float* __restrict__ uh = u + half * 1000;
      float s[5][4];
#pragma unroll
      for (int k = 0; k < 5; k++)
#pragma unroll
        for (int i = 0; i < 4; i++)
          s[k][i] = vld[i] ? uh[k * 200 + lane + 64 * i] : 0.5f;

      // s = el / log2(u)^2  (ln^2(2) cancels in softmax; invalid lanes ->
      // u=0.5 -> q=-1 -> rcp(1)=1, times el=0 -> 0)
#pragma unroll
      for (int k = 0; k < 5; k++)
#pragma unroll
        for (int i = 0; i < 4; i++) {
          const float q = __log2f(fmaxf(s[k][i], EPS));
          s[k][i] = el[i] * __builtin_amdgcn_rcpf(q * q);
        }

      // 5 independent butterfly reductions, interleaved
      float ps[5];
#pragma unroll
      for (int k = 0; k < 5; k++) ps[k] = (s[k][0] + s[k][1]) + (s[k][2] + s[k][3]);
#pragma unroll
      for (int off = 32; off > 0; off >>= 1)
#pragma unroll
        for (int k = 0; k < 5; k++) ps[k] += __shfl_xor(ps[k], off, 64);
#pragma unroll
      for (int k = 0; k < 5; k++) ps[k] = __builtin_amdgcn_rcpf(ps[k]);

#pragma unroll
      for (int k = 0; k < 5; k++)
#pragma unroll
        for (int i = 0; i < 4; i++) smax[i] = fmaxf(smax[i], s[k][i] * ps[k]);
    }

    // Head: load x only now (not live across the sampling loop)
    float p0 = 0.0f, p1 = 0.0f;
#pragma unroll
    for (int i = 0; i < 4; i++) {
      const int d = lane + 64 * i;
      if (d < 200) {
        const float sv = smax[i];
        __builtin_nontemporal_store(sv, &out[samplesBase + (size_t)b * 200 + d]);
        const float xs = x[(size_t)b * 200 + d] * sv;
        p0 += xs * wo[d * 2 + 0];
        p1 += xs * wo[d * 2 + 1];
      }
    }
#pragma unroll
    for (int off = 32; off > 0; off >>= 1) {
      p0 += __shfl_xor(p0, off, 64);
      p1 += __shfl_xor(p1, off, 64);
    }
    if (lane == 0) {
      const float z0 = p0 + bo[0];
      const float z1 = p1 + bo[1];
      const float mh = fmaxf(z0, z1);
      const float e0 = __expf(z0 - mh);
      const float e1 = __expf(z1 - mh);
      out[b * 2 + 0] = e0 / (e0 + e1);
      out[b * 2 + 1] = e1 / (e0 + e1);
    }
  }
}

extern "C" void kernel_launch(void* const* d_in, const int* in_sizes, int n_in,
                              void* d_out, int out_size, void* d_ws, size_t ws_size,
                              hipStream_t stream) {
  const float* x  = (const float*)d_in[0];
  const float* un = (const float*)d_in[1];
  const float* w1 = (const float*)d_in[2];
  const float* b1 = (const float*)d_in[3];
  const float* w2 = (const float*)d_in[4];
  const float* b2 = (const float*)d_in[5];
  const float* wl = (const float*)d_in[6];
  const float* bl = (const float*)d_in[7];
  const float* wo = (const float*)d_in[8];
  const float* bo = (const float*)d_in[9];
  float* out = (float*)d_out;

  const int B = in_sizes[0] / 200;  // 32768
  float* h2 = (float*)d_ws;         // B*100 fp32 = 13.1 MB

  fused_mlp12<<<B / 64, 256, 0, stream>>>(x, w1, b1, w2, b2, h2);
  fused_logits_concrete<<<B / 32, 512, 0, stream>>>(x, un, h2, wl, bl, wo, bo, out, B);
}